// Round 5
// baseline (1475.360 us; speedup 1.0000x reference)
//
#include <hip/hip_runtime.h>
#include <hip/hip_bf16.h>

#define TT 6
#define NN 50000
#define EE 800000
#define FF 32
#define HH 64
#define OO 16

#define NB 256        // dst buckets
#define DPB 196       // dsts per bucket (256*196 = 50176 >= 50000)
#define CHUNK 4096    // edges per block in hist/scatter

// fused weight buffer layout (float offsets)
#define OFF_M 0        // M[g][32][64], g = z,r,h : W_g @ L_g[:64]
#define OFF_B 6144     // B[g][64][64]            : L_g[64:]
#define OFF_C 18432    // c[g][64]                : b_g @ L_g[:64] + L_g_b
#define OFF_OW 18624   // out_W [64][16]
#define OFF_OB 19648   // out_b [16]
#define WBUF_N 19664

typedef unsigned short ushort_t;

__device__ __forceinline__ float ldf(const void* p, int i){ return ((const float*)p)[i]; }
// bf16 (as ushort) -> f32
__device__ __forceinline__ float ubf(ushort_t v){ return __uint_as_float(((unsigned)v) << 16); }
// f32 -> bf16 bits, RNE
__device__ __forceinline__ ushort_t f2b(float f){
  unsigned u = __float_as_uint(f);
  return (ushort_t)((u + 0x7FFFu + ((u >> 16) & 1u)) >> 16);
}
__device__ __forceinline__ float lo16(unsigned u){ return __uint_as_float(u << 16); }
__device__ __forceinline__ float hi16(unsigned u){ return __uint_as_float(u & 0xFFFF0000u); }

// ---------------- zero ----------------
__global__ void zero_kernel(uint4* __restrict__ p, int n4){
  int i = blockIdx.x*256 + threadIdx.x;
  if (i < n4) p[i] = make_uint4(0,0,0,0);
}

// ---------------- f32 -> bf16 convert (xs -> xb), 4 elems/thread ----------------
__global__ void cvt_kernel(const float4* __restrict__ x, ushort4* __restrict__ xb, int n4){
  int i = blockIdx.x*256 + threadIdx.x;
  if (i < n4){
    float4 v = x[i];
    ushort4 o;
    o.x = f2b(v.x); o.y = f2b(v.y); o.z = f2b(v.z); o.w = f2b(v.w);
    xb[i] = o;
  }
}

// ---------------- fused-weight prep (all inputs f32) ----------------
__global__ void prep_kernel(const void* Wz,const void* bz,const void* Wr,const void* br,
                            const void* Wh,const void* bh,
                            const void* Lz,const void* Lzb,const void* Lr,const void* Lrb,
                            const void* Lh,const void* Lhb,
                            const void* oW,const void* ob, float* __restrict__ wbuf){
  int idx = blockIdx.x*256 + threadIdx.x;
  if (idx >= WBUF_N) return;
  if (idx < OFF_B){                       // M[g][k][j] = sum_m W[k][m] * L[m][j]
    int g = idx >> 11; int r = idx & 2047; int k = r >> 6; int j = r & 63;
    const void* W = (g==0)?Wz:((g==1)?Wr:Wh);
    const void* L = (g==0)?Lz:((g==1)?Lr:Lh);
    float s = 0.f;
    for (int m=0;m<64;m++) s += ldf(W,k*64+m) * ldf(L,m*64+j);
    wbuf[idx] = s;
  } else if (idx < OFF_C){                // B[g][k][j] = L[(64+k)][j]
    int i = idx - OFF_B; int g = i >> 12; int r = i & 4095; int k = r >> 6; int j = r & 63;
    const void* L = (g==0)?Lz:((g==1)?Lr:Lh);
    wbuf[idx] = ldf(L,(64+k)*64 + j);
  } else if (idx < OFF_OW){               // c[g][j] = sum_m b[m]*L[m][j] + Lb[j]
    int i = idx - OFF_C; int g = i >> 6; int j = i & 63;
    const void* L  = (g==0)?Lz:((g==1)?Lr:Lh);
    const void* bb = (g==0)?bz:((g==1)?br:bh);
    const void* Lb = (g==0)?Lzb:((g==1)?Lrb:Lhb);
    float s = ldf(Lb,j);
    for (int m=0;m<64;m++) s += ldf(bb,m) * ldf(L,m*64+j);
    wbuf[idx] = s;
  } else if (idx < OFF_OB){
    wbuf[idx] = ldf(oW,idx - OFF_OW);
  } else {
    wbuf[idx] = ldf(ob,idx - OFF_OB);
  }
}

// ---------------- pass 1: per-t bucket histogram ----------------
__global__ __launch_bounds__(256) void hist_kernel(const int* __restrict__ ei,
                                                   int* __restrict__ bcnt){
  int t = blockIdx.y;
  __shared__ int cnt[NB];
  int tid = threadIdx.x;
  cnt[tid] = 0;
  __syncthreads();
  int e0 = blockIdx.x*CHUNK;
  const int* dsts = ei + t*2*EE + EE;
  #pragma unroll
  for (int i = 0; i < CHUNK/256; i++){
    int e = e0 + i*256 + tid;
    if (e < EE) atomicAdd(&cnt[dsts[e]/DPB], 1);
  }
  __syncthreads();
  if (cnt[tid] > 0) atomicAdd(&bcnt[t*NB + tid], cnt[tid]);
}

// ---------------- pass 2: scan bucket counts -> starts & cursors ----------------
__global__ __launch_bounds__(256) void bscan_kernel(const int* __restrict__ bcnt,
                                                    int* __restrict__ bstart,
                                                    int* __restrict__ bcur){
  int t = blockIdx.x;
  int tid = threadIdx.x;
  int v = bcnt[t*NB + tid];
  int lane = tid & 63, wid = tid >> 6;
  int x = v;
  #pragma unroll
  for (int off = 1; off < 64; off <<= 1){
    int y = __shfl_up(x, off, 64);
    if (lane >= off) x += y;
  }
  __shared__ int wsum[4];
  if (lane == 63) wsum[wid] = x;
  __syncthreads();
  if (tid == 0){
    int s = 0;
    #pragma unroll
    for (int w = 0; w < 4; w++){ int tmp = wsum[w]; wsum[w] = s; s += tmp; }
  }
  __syncthreads();
  int excl = x - v + wsum[wid];
  bstart[t*(NB+1) + tid] = excl;
  bcur[t*NB + tid] = excl;
  if (tid == NB-1) bstart[t*(NB+1) + NB] = excl + v;   // == EE
}

// ---------------- pass 3: block-aggregated scatter into bucket runs ----------------
// packed entry: (dstlo << 16) | src   (src < 50000 < 2^16, dstlo < 196)
__global__ __launch_bounds__(256) void scatter_kernel(const int* __restrict__ ei,
                                                      int* __restrict__ bcur,
                                                      unsigned int* __restrict__ csrp){
  int t = blockIdx.y;
  __shared__ int cnt[NB];
  __shared__ int base[NB];
  int tid = threadIdx.x;
  cnt[tid] = 0;
  __syncthreads();
  int e0 = blockIdx.x*CHUNK;
  const int* srcs = ei + t*2*EE;
  const int* dsts = ei + t*2*EE + EE;
  int pk[CHUNK/256];        // (b<<12) | local_rank
  unsigned int pay[CHUNK/256];
  #pragma unroll
  for (int i = 0; i < CHUNK/256; i++){
    int e = e0 + i*256 + tid;
    if (e < EE){
      int s = srcs[e], d = dsts[e];
      int b = d / DPB;
      int lr = atomicAdd(&cnt[b], 1);
      pk[i] = (b << 12) | lr;
      pay[i] = ((unsigned)(d - b*DPB) << 16) | (unsigned)s;
    } else pk[i] = -1;
  }
  __syncthreads();
  if (cnt[tid] > 0) base[tid] = atomicAdd(&bcur[t*NB + tid], cnt[tid]);
  __syncthreads();
  unsigned int* cp = csrp + (size_t)t*EE;
  #pragma unroll
  for (int i = 0; i < CHUNK/256; i++){
    if (pk[i] >= 0){
      int b = pk[i] >> 12, lr = pk[i] & 4095;
      cp[base[b] + lr] = pay[i];
    }
  }
}

// ---------------- pass 4: per-bucket degree -> dinv ----------------
__global__ __launch_bounds__(256) void degdinv_kernel(const unsigned int* __restrict__ csrp,
                                                      const int* __restrict__ bstart,
                                                      float* __restrict__ dinv){
  int b = blockIdx.x, t = blockIdx.y, tid = threadIdx.x;
  __shared__ int cnt[DPB];
  for (int i = tid; i < DPB; i += 256) cnt[i] = 0;
  __syncthreads();
  int b0 = bstart[t*(NB+1) + b], b1 = bstart[t*(NB+1) + b + 1];
  const unsigned int* cp = csrp + (size_t)t*EE;
  for (int i = b0 + tid; i < b1; i += 256)
    atomicAdd(&cnt[cp[i] >> 16], 1);
  __syncthreads();
  for (int i = tid; i < DPB; i += 256){
    int n = b*DPB + i;
    if (n < NN) dinv[t*NN + n] = rsqrtf((float)(cnt[i] + 1));  // +1 self loop
  }
}

// ---------------- pass 5: bucket-fused gather, lane-per-edge MLP version ------
// agg[t][n][f] = dinv[n]*( dinv[n]*x[n][f] + sum_s dinv[s]*x[s][f] )
// 4 lanes per edge (16 B bf16 row chunk each); 16 edges in flight per wave instr.
__global__ __launch_bounds__(256) void gatherb_kernel(const float* __restrict__ xs,
                                                      const ushort_t* __restrict__ xb,
                                                      const float* __restrict__ dinv,
                                                      const unsigned int* __restrict__ csrp,
                                                      const int* __restrict__ bstart,
                                                      ushort_t* __restrict__ aggb){
  int b = blockIdx.x, t = blockIdx.y, tid = threadIdx.x;
  __shared__ float acc[DPB][FF+1];          // +1 pad: atomics spread across banks
  for (int i = tid; i < DPB*(FF+1); i += 256) ((float*)acc)[i] = 0.f;
  __syncthreads();
  int b0 = bstart[t*(NB+1) + b], b1 = bstart[t*(NB+1) + b + 1];
  const float* dv = dinv + t*NN;
  const unsigned int* cp = csrp + (size_t)t*EE;
  const ushort_t* xbt = xb + (size_t)t*NN*FF;
  int w = tid >> 6, lane = tid & 63;
  int er = lane >> 2;                       // edge rank within wave (0..15)
  int qf = lane & 3;                        // quarter-row (8 bf16 = 16 B)
  int base = b0 + (w << 4);
  int e = base + er;
  bool val = (e < b1);
  unsigned p = val ? cp[e] : 0u;            // software-pipelined packed edge
  while (base < b1){
    int nbase = base + 64;
    int ne = nbase + er;
    bool nval = (ne < b1);
    unsigned np = nval ? cp[ne] : 0u;       // prefetch next (independent)
    int s = p & 0xFFFFu;
    int dlo = p >> 16;
    float dvs = val ? dv[s] : 0.f;
    uint4 rv = make_uint4(0,0,0,0);
    if (val) rv = *(const uint4*)(xbt + (size_t)s*FF + (qf << 3));
    if (val){
      int fb = qf << 3;
      atomicAdd(&acc[dlo][fb+0], dvs * lo16(rv.x));
      atomicAdd(&acc[dlo][fb+1], dvs * hi16(rv.x));
      atomicAdd(&acc[dlo][fb+2], dvs * lo16(rv.y));
      atomicAdd(&acc[dlo][fb+3], dvs * hi16(rv.y));
      atomicAdd(&acc[dlo][fb+4], dvs * lo16(rv.z));
      atomicAdd(&acc[dlo][fb+5], dvs * hi16(rv.z));
      atomicAdd(&acc[dlo][fb+6], dvs * lo16(rv.w));
      atomicAdd(&acc[dlo][fb+7], dvs * hi16(rv.w));
    }
    base = nbase; p = np; val = nval;
  }
  __syncthreads();
  int f = tid & 31;
  for (int i = tid >> 5; i < DPB; i += 8){
    int n = b*DPB + i;
    if (n < NN){
      float dn = dv[n];
      float v = dn*(acc[i][f] + dn*xs[((size_t)t*NN + n)*FF + f]);  // self term f32
      aggb[((size_t)t*NN + n)*FF + f] = f2b(v);
    }
  }
}

// ---------------- fused GRU step: R, Z, Htilde, h update (node-local) ----------------
__global__ __launch_bounds__(256) void gate_kernel(const ushort_t* __restrict__ aggt,
                                                   float* __restrict__ h,
                                                   const float* __restrict__ w){
  __shared__ float As[64][33];
  __shared__ float Hs[64][65];
  __shared__ float HRs[64][65];
  int tid = threadIdx.x;
  int nb = blockIdx.x*64;
  #pragma unroll
  for (int r = 0; r < 8; r++){
    int i = tid + 256*r; int n = i >> 5, k = i & 31; int gn = nb + n;
    As[n][k] = (gn < NN) ? ubf(aggt[gn*FF + k]) : 0.f;
  }
  #pragma unroll
  for (int r = 0; r < 16; r++){
    int i = tid + 256*r; int n = i >> 6, k = i & 63; int gn = nb + n;
    Hs[n][k] = (gn < NN) ? h[gn*HH + k] : 0.f;
  }
  __syncthreads();
  int node = tid & 63;
  int j0 = __builtin_amdgcn_readfirstlane((tid >> 6) * 16);  // wave-uniform

  // ---- R = sigmoid(agg@Mr + h@Br + cr); stage h*R to LDS ----
  float acc[16];
  #pragma unroll
  for (int jj = 0; jj < 16; jj++) acc[jj] = w[OFF_C + 64 + j0 + jj];
  #pragma unroll
  for (int k = 0; k < 32; k++){
    float a = As[node][k];
    const float* wr = w + OFF_M + 2048 + k*64 + j0;
    #pragma unroll
    for (int jj = 0; jj < 16; jj++) acc[jj] += a * wr[jj];
  }
  #pragma unroll
  for (int k = 0; k < 64; k++){
    float a = Hs[node][k];
    const float* wr = w + OFF_B + 4096 + k*64 + j0;
    #pragma unroll
    for (int jj = 0; jj < 16; jj++) acc[jj] += a * wr[jj];
  }
  #pragma unroll
  for (int jj = 0; jj < 16; jj++){
    float rr = 1.f / (1.f + __expf(-acc[jj]));
    HRs[node][j0 + jj] = Hs[node][j0 + jj] * rr;
  }
  __syncthreads();

  // ---- Z and Htilde together ----
  float az[16], ah[16];
  #pragma unroll
  for (int jj = 0; jj < 16; jj++){
    az[jj] = w[OFF_C + j0 + jj];
    ah[jj] = w[OFF_C + 128 + j0 + jj];
  }
  #pragma unroll
  for (int k = 0; k < 32; k++){
    float a = As[node][k];
    const float* wz = w + OFF_M + k*64 + j0;
    const float* wh = w + OFF_M + 4096 + k*64 + j0;
    #pragma unroll
    for (int jj = 0; jj < 16; jj++){ az[jj] += a*wz[jj]; ah[jj] += a*wh[jj]; }
  }
  #pragma unroll
  for (int k = 0; k < 64; k++){
    float hk  = Hs[node][k];
    float hrk = HRs[node][k];
    const float* wz = w + OFF_B + k*64 + j0;
    const float* wh = w + OFF_B + 8192 + k*64 + j0;
    #pragma unroll
    for (int jj = 0; jj < 16; jj++){ az[jj] += hk*wz[jj]; ah[jj] += hrk*wh[jj]; }
  }
  float hnew[16];
  #pragma unroll
  for (int jj = 0; jj < 16; jj++){
    float z = 1.f / (1.f + __expf(-az[jj]));
    float x = ah[jj];
    float e = __expf(-2.f * fabsf(x));
    float th = (1.f - e) / (1.f + e);
    th = (x < 0.f) ? -th : th;
    hnew[jj] = z * Hs[node][j0 + jj] + (1.f - z) * th;
  }
  __syncthreads();                          // all HRs reads done
  #pragma unroll
  for (int jj = 0; jj < 16; jj++) HRs[node][j0 + jj] = hnew[jj];
  __syncthreads();
  #pragma unroll
  for (int r = 0; r < 16; r++){
    int i = tid + 256*r; int n = i >> 6, k = i & 63; int gn = nb + n;
    if (gn < NN) h[gn*HH + k] = HRs[n][k];
  }
}

// ---------------- final projection h @ out_W + out_b -> f32 ----------------
__global__ __launch_bounds__(256) void out_kernel(const float* __restrict__ h,
                                                  const float* __restrict__ w,
                                                  float* __restrict__ out){
  __shared__ float Hl[16][65];
  __shared__ float Wl[64][16];
  __shared__ float bl[16];
  int tid = threadIdx.x;
  int nb = blockIdx.x*16;
  #pragma unroll
  for (int r = 0; r < 4; r++){
    int i = tid + 256*r;
    int n = i >> 6, k = i & 63; int gn = nb + n;
    Hl[n][k] = (gn < NN) ? h[gn*HH + k] : 0.f;
    Wl[(i >> 4) & 63][i & 15] = w[OFF_OW + i];
  }
  if (tid < 16) bl[tid] = w[OFF_OB + tid];
  __syncthreads();
  int n = tid >> 4; int o = tid & 15;
  float acc = bl[o];
  #pragma unroll
  for (int k = 0; k < 64; k++) acc += Hl[n][k] * Wl[k][o];
  int gn = nb + n;
  if (gn < NN) out[gn*OO + o] = acc;
}

extern "C" void kernel_launch(void* const* d_in, const int* in_sizes, int n_in,
                              void* d_out, int out_size, void* d_ws, size_t ws_size,
                              hipStream_t stream) {
  const float* xs = (const float*)d_in[0];
  const int*   ei = (const int*)d_in[1];
  float* out = (float*)d_out;
  char* ws = (char*)d_ws;
  // workspace layout (bytes); total 71,702,656 (same footprint as round-4-proven)
  ushort_t*     aggb   = (ushort_t*)(ws + 0);            // 19,200,000
  ushort_t*     xb     = (ushort_t*)(ws + 19200000);     // 19,200,000
  unsigned int* csrp   = (unsigned int*)(ws + 38400000); // 19,200,000
  float*        h      = (float*)(ws + 57600000);        // 12,800,000
  float*        dinv   = (float*)(ws + 70400000);        //  1,200,000
  int*          bcnt   = (int*)  (ws + 71600000);        // 6144
  int*          bstart = (int*)  (ws + 71608000);        // 6168
  int*          bcur   = (int*)  (ws + 71616000);        // 6144
  float*        wbuf   = (float*)(ws + 71624000);        // 78,656 -> end 71,702,656

  zero_kernel<<<(800000 + 255)/256, 256, 0, stream>>>((uint4*)(ws + 57600000), 800000); // h
  zero_kernel<<<2, 256, 0, stream>>>((uint4*)(ws + 71600000), 384);                      // bcnt
  cvt_kernel<<<(2400000 + 255)/256, 256, 0, stream>>>((const float4*)xs, (ushort4*)xb, 2400000);
  prep_kernel<<<(WBUF_N + 255)/256, 256, 0, stream>>>(d_in[2],d_in[3],d_in[4],d_in[5],
      d_in[6],d_in[7],d_in[8],d_in[9],d_in[10],d_in[11],d_in[12],d_in[13],d_in[14],d_in[15],
      wbuf);
  hist_kernel<<<dim3((EE + CHUNK-1)/CHUNK, TT), 256, 0, stream>>>(ei, bcnt);
  bscan_kernel<<<TT, 256, 0, stream>>>(bcnt, bstart, bcur);
  scatter_kernel<<<dim3((EE + CHUNK-1)/CHUNK, TT), 256, 0, stream>>>(ei, bcur, csrp);
  degdinv_kernel<<<dim3(NB, TT), 256, 0, stream>>>(csrp, bstart, dinv);
  gatherb_kernel<<<dim3(NB, TT), 256, 0, stream>>>(xs, xb, dinv, csrp, bstart, aggb);
  for (int t = 0; t < TT; t++)
    gate_kernel<<<(NN + 63)/64, 256, 0, stream>>>(aggb + (size_t)t*NN*FF, h, wbuf);
  out_kernel<<<NN/16, 256, 0, stream>>>(h, wbuf, out);
}

// Round 6
// 886.339 us; speedup vs baseline: 1.6646x; 1.6646x over previous
//
#include <hip/hip_runtime.h>
#include <hip/hip_bf16.h>

#define TT 6
#define NN 50000
#define EE 800000
#define FF 32
#define HH 64
#define OO 16

#define NB 256        // dst buckets
#define DPB 196       // dsts per bucket (256*196 = 50176 >= 50000)
#define CHUNK 4096    // edges per block in hist/scatter
#define SCAP 8192     // sorted-edge LDS capacity per bucket (mean 3125, 90 sigma)

// fused weight buffer layout (float offsets)
#define OFF_M 0        // M[g][32][64], g = z,r,h : W_g @ L_g[:64]
#define OFF_B 6144     // B[g][64][64]            : L_g[64:]
#define OFF_C 18432    // c[g][64]                : b_g @ L_g[:64] + L_g_b
#define OFF_OW 18624   // out_W [64][16]
#define OFF_OB 19648   // out_b [16]
#define WBUF_N 19664

typedef unsigned short ushort_t;

__device__ __forceinline__ float ldf(const void* p, int i){ return ((const float*)p)[i]; }
// bf16 (as ushort) -> f32
__device__ __forceinline__ float ubf(ushort_t v){ return __uint_as_float(((unsigned)v) << 16); }
// f32 -> bf16 bits, RNE
__device__ __forceinline__ ushort_t f2b(float f){
  unsigned u = __float_as_uint(f);
  return (ushort_t)((u + 0x7FFFu + ((u >> 16) & 1u)) >> 16);
}

// ---------------- zero ----------------
__global__ void zero_kernel(uint4* __restrict__ p, int n4){
  int i = blockIdx.x*256 + threadIdx.x;
  if (i < n4) p[i] = make_uint4(0,0,0,0);
}

// ---------------- f32 -> bf16 convert (xs -> xb), 4 elems/thread ----------------
__global__ void cvt_kernel(const float4* __restrict__ x, ushort4* __restrict__ xb, int n4){
  int i = blockIdx.x*256 + threadIdx.x;
  if (i < n4){
    float4 v = x[i];
    ushort4 o;
    o.x = f2b(v.x); o.y = f2b(v.y); o.z = f2b(v.z); o.w = f2b(v.w);
    xb[i] = o;
  }
}

// ---------------- fused-weight prep (all inputs f32) ----------------
__global__ void prep_kernel(const void* Wz,const void* bz,const void* Wr,const void* br,
                            const void* Wh,const void* bh,
                            const void* Lz,const void* Lzb,const void* Lr,const void* Lrb,
                            const void* Lh,const void* Lhb,
                            const void* oW,const void* ob, float* __restrict__ wbuf){
  int idx = blockIdx.x*256 + threadIdx.x;
  if (idx >= WBUF_N) return;
  if (idx < OFF_B){                       // M[g][k][j] = sum_m W[k][m] * L[m][j]
    int g = idx >> 11; int r = idx & 2047; int k = r >> 6; int j = r & 63;
    const void* W = (g==0)?Wz:((g==1)?Wr:Wh);
    const void* L = (g==0)?Lz:((g==1)?Lr:Lh);
    float s = 0.f;
    for (int m=0;m<64;m++) s += ldf(W,k*64+m) * ldf(L,m*64+j);
    wbuf[idx] = s;
  } else if (idx < OFF_C){                // B[g][k][j] = L[(64+k)][j]
    int i = idx - OFF_B; int g = i >> 12; int r = i & 4095; int k = r >> 6; int j = r & 63;
    const void* L = (g==0)?Lz:((g==1)?Lr:Lh);
    wbuf[idx] = ldf(L,(64+k)*64 + j);
  } else if (idx < OFF_OW){               // c[g][j] = sum_m b[m]*L[m][j] + Lb[j]
    int i = idx - OFF_C; int g = i >> 6; int j = i & 63;
    const void* L  = (g==0)?Lz:((g==1)?Lr:Lh);
    const void* bb = (g==0)?bz:((g==1)?br:bh);
    const void* Lb = (g==0)?Lzb:((g==1)?Lrb:Lhb);
    float s = ldf(Lb,j);
    for (int m=0;m<64;m++) s += ldf(bb,m) * ldf(L,m*64+j);
    wbuf[idx] = s;
  } else if (idx < OFF_OB){
    wbuf[idx] = ldf(oW,idx - OFF_OW);
  } else {
    wbuf[idx] = ldf(ob,idx - OFF_OB);
  }
}

// ---------------- pass 1: per-t bucket histogram ----------------
__global__ __launch_bounds__(256) void hist_kernel(const int* __restrict__ ei,
                                                   int* __restrict__ bcnt){
  int t = blockIdx.y;
  __shared__ int cnt[NB];
  int tid = threadIdx.x;
  cnt[tid] = 0;
  __syncthreads();
  int e0 = blockIdx.x*CHUNK;
  const int* dsts = ei + t*2*EE + EE;
  #pragma unroll
  for (int i = 0; i < CHUNK/256; i++){
    int e = e0 + i*256 + tid;
    if (e < EE) atomicAdd(&cnt[dsts[e]/DPB], 1);
  }
  __syncthreads();
  if (cnt[tid] > 0) atomicAdd(&bcnt[t*NB + tid], cnt[tid]);
}

// ---------------- pass 2: scan bucket counts -> starts & cursors ----------------
__global__ __launch_bounds__(256) void bscan_kernel(const int* __restrict__ bcnt,
                                                    int* __restrict__ bstart,
                                                    int* __restrict__ bcur){
  int t = blockIdx.x;
  int tid = threadIdx.x;
  int v = bcnt[t*NB + tid];
  int lane = tid & 63, wid = tid >> 6;
  int x = v;
  #pragma unroll
  for (int off = 1; off < 64; off <<= 1){
    int y = __shfl_up(x, off, 64);
    if (lane >= off) x += y;
  }
  __shared__ int wsum[4];
  if (lane == 63) wsum[wid] = x;
  __syncthreads();
  if (tid == 0){
    int s = 0;
    #pragma unroll
    for (int w = 0; w < 4; w++){ int tmp = wsum[w]; wsum[w] = s; s += tmp; }
  }
  __syncthreads();
  int excl = x - v + wsum[wid];
  bstart[t*(NB+1) + tid] = excl;
  bcur[t*NB + tid] = excl;
  if (tid == NB-1) bstart[t*(NB+1) + NB] = excl + v;   // == EE
}

// ---------------- pass 3: block-aggregated scatter into bucket runs ----------------
// packed entry: (dstlo << 16) | src   (src < 50000 < 2^16, dstlo < 196)
__global__ __launch_bounds__(256) void scatter_kernel(const int* __restrict__ ei,
                                                      int* __restrict__ bcur,
                                                      unsigned int* __restrict__ csrp){
  int t = blockIdx.y;
  __shared__ int cnt[NB];
  __shared__ int base[NB];
  int tid = threadIdx.x;
  cnt[tid] = 0;
  __syncthreads();
  int e0 = blockIdx.x*CHUNK;
  const int* srcs = ei + t*2*EE;
  const int* dsts = ei + t*2*EE + EE;
  int pk[CHUNK/256];        // (b<<12) | local_rank
  unsigned int pay[CHUNK/256];
  #pragma unroll
  for (int i = 0; i < CHUNK/256; i++){
    int e = e0 + i*256 + tid;
    if (e < EE){
      int s = srcs[e], d = dsts[e];
      int b = d / DPB;
      int lr = atomicAdd(&cnt[b], 1);
      pk[i] = (b << 12) | lr;
      pay[i] = ((unsigned)(d - b*DPB) << 16) | (unsigned)s;
    } else pk[i] = -1;
  }
  __syncthreads();
  if (cnt[tid] > 0) base[tid] = atomicAdd(&bcur[t*NB + tid], cnt[tid]);
  __syncthreads();
  unsigned int* cp = csrp + (size_t)t*EE;
  #pragma unroll
  for (int i = 0; i < CHUNK/256; i++){
    if (pk[i] >= 0){
      int b = pk[i] >> 12, lr = pk[i] & 4095;
      cp[base[b] + lr] = pay[i];
    }
  }
}

// ---------------- pass 4: per-bucket degree -> dinv ----------------
__global__ __launch_bounds__(256) void degdinv_kernel(const unsigned int* __restrict__ csrp,
                                                      const int* __restrict__ bstart,
                                                      float* __restrict__ dinv){
  int b = blockIdx.x, t = blockIdx.y, tid = threadIdx.x;
  __shared__ int cnt[DPB];
  for (int i = tid; i < DPB; i += 256) cnt[i] = 0;
  __syncthreads();
  int b0 = bstart[t*(NB+1) + b], b1 = bstart[t*(NB+1) + b + 1];
  const unsigned int* cp = csrp + (size_t)t*EE;
  for (int i = b0 + tid; i < b1; i += 256)
    atomicAdd(&cnt[cp[i] >> 16], 1);
  __syncthreads();
  for (int i = tid; i < DPB; i += 256){
    int n = b*DPB + i;
    if (n < NN) dinv[t*NN + n] = rsqrtf((float)(cnt[i] + 1));  // +1 self loop
  }
}

// ---------------- pass 5: bucket gather, counting-sort + register reduce -------
// NO floating-point LDS atomics: sort bucket edges by dst (int atomics only),
// then each wave reduces its 49-dst range in registers (2 edges x 32 feat lanes).
// agg[t][n][f] = dinv[n]*( dinv[n]*x[n][f] + sum_s dinv[s]*x[s][f] )
__global__ __launch_bounds__(256) void gatherb_kernel(const float* __restrict__ xs,
                                                      const ushort_t* __restrict__ xb,
                                                      const float* __restrict__ dinv,
                                                      const unsigned int* __restrict__ csrp,
                                                      const int* __restrict__ bstart,
                                                      ushort_t* __restrict__ aggb){
  int b = blockIdx.x, t = blockIdx.y, tid = threadIdx.x;
  __shared__ ushort_t ssrc[SCAP];          // 16 KB: srcs sorted by dstlo
  __shared__ int cnt[DPB];                 // histogram, then rank cursor
  __shared__ int off[DPB+1];
  __shared__ int wsum[4];
  for (int i = tid; i < DPB; i += 256) cnt[i] = 0;
  __syncthreads();
  int b0 = bstart[t*(NB+1) + b], b1 = bstart[t*(NB+1) + b + 1];
  const unsigned int* cp = csrp + (size_t)t*EE;
  // histogram by dstlo (native int LDS atomics)
  for (int e = b0 + tid; e < b1; e += 256)
    atomicAdd(&cnt[cp[e] >> 16], 1);
  __syncthreads();
  // exclusive scan cnt[0..195]
  int v = (tid < DPB) ? cnt[tid] : 0;
  int lane = tid & 63, wid = tid >> 6;
  int x = v;
  #pragma unroll
  for (int o = 1; o < 64; o <<= 1){
    int y = __shfl_up(x, o, 64);
    if (lane >= o) x += y;
  }
  if (lane == 63) wsum[wid] = x;
  __syncthreads();
  if (tid == 0){
    int s = 0;
    #pragma unroll
    for (int w = 0; w < 4; w++){ int tmp = wsum[w]; wsum[w] = s; s += tmp; }
  }
  __syncthreads();
  int excl = x - v + wsum[wid];
  if (tid < DPB){ off[tid] = excl; cnt[tid] = excl; }   // cnt becomes cursor
  if (tid == DPB-1) off[DPB] = excl + v;
  __syncthreads();
  // rank & sorted write (int atomics + u16 LDS stores)
  for (int e = b0 + tid; e < b1; e += 256){
    unsigned p = cp[e];
    int r = atomicAdd(&cnt[p >> 16], 1);
    if (r < SCAP) ssrc[r] = (ushort_t)(p & 0xFFFFu);
  }
  __syncthreads();
  // register reduction: wave w owns dsts [w*49, w*49+49); 64 lanes = 2 edges x 32 f
  int w = tid >> 6;
  int eh = (tid >> 5) & 1;
  int f = tid & 31;
  const ushort_t* xbt = xb + (size_t)t*NN*FF;
  const float* dv = dinv + t*NN;
  for (int d = w*49; d < w*49 + 49; d++){
    int e0 = off[d], e1 = off[d+1];
    float accf = 0.f;
    int i = e0 + eh;
    int scur = (i < e1) ? (int)ssrc[i] : 0;   // broadcast LDS read
    while (i < e1){
      int inext = i + 2;
      int snxt = (inext < e1) ? (int)ssrc[inext] : 0;   // prefetch
      float dvs = dv[scur];                              // 32-lane broadcast line
      float xv = ubf(xbt[(size_t)scur*FF + f]);          // full 64 B line / edge
      accf += dvs * xv;
      i = inext; scur = snxt;
    }
    float sum = accf + __shfl_xor(accf, 32, 64);
    int n = b*DPB + d;
    if (eh == 0 && n < NN){
      float dn = dv[n];
      float sv = xs[((size_t)t*NN + n)*FF + f];          // self term, f32
      aggb[((size_t)t*NN + n)*FF + f] = f2b(dn*(sum + dn*sv));
    }
  }
}

// ---------------- fused GRU step: R, Z, Htilde, h update (node-local) ----------------
__global__ __launch_bounds__(256) void gate_kernel(const ushort_t* __restrict__ aggt,
                                                   float* __restrict__ h,
                                                   const float* __restrict__ w){
  __shared__ float As[64][33];
  __shared__ float Hs[64][65];
  __shared__ float HRs[64][65];
  int tid = threadIdx.x;
  int nb = blockIdx.x*64;
  #pragma unroll
  for (int r = 0; r < 8; r++){
    int i = tid + 256*r; int n = i >> 5, k = i & 31; int gn = nb + n;
    As[n][k] = (gn < NN) ? ubf(aggt[gn*FF + k]) : 0.f;
  }
  #pragma unroll
  for (int r = 0; r < 16; r++){
    int i = tid + 256*r; int n = i >> 6, k = i & 63; int gn = nb + n;
    Hs[n][k] = (gn < NN) ? h[gn*HH + k] : 0.f;
  }
  __syncthreads();
  int node = tid & 63;
  int j0 = __builtin_amdgcn_readfirstlane((tid >> 6) * 16);  // wave-uniform

  // ---- R = sigmoid(agg@Mr + h@Br + cr); stage h*R to LDS ----
  float acc[16];
  #pragma unroll
  for (int jj = 0; jj < 16; jj++) acc[jj] = w[OFF_C + 64 + j0 + jj];
  #pragma unroll
  for (int k = 0; k < 32; k++){
    float a = As[node][k];
    const float* wr = w + OFF_M + 2048 + k*64 + j0;
    #pragma unroll
    for (int jj = 0; jj < 16; jj++) acc[jj] += a * wr[jj];
  }
  #pragma unroll
  for (int k = 0; k < 64; k++){
    float a = Hs[node][k];
    const float* wr = w + OFF_B + 4096 + k*64 + j0;
    #pragma unroll
    for (int jj = 0; jj < 16; jj++) acc[jj] += a * wr[jj];
  }
  #pragma unroll
  for (int jj = 0; jj < 16; jj++){
    float rr = 1.f / (1.f + __expf(-acc[jj]));
    HRs[node][j0 + jj] = Hs[node][j0 + jj] * rr;
  }
  __syncthreads();

  // ---- Z and Htilde together ----
  float az[16], ah[16];
  #pragma unroll
  for (int jj = 0; jj < 16; jj++){
    az[jj] = w[OFF_C + j0 + jj];
    ah[jj] = w[OFF_C + 128 + j0 + jj];
  }
  #pragma unroll
  for (int k = 0; k < 32; k++){
    float a = As[node][k];
    const float* wz = w + OFF_M + k*64 + j0;
    const float* wh = w + OFF_M + 4096 + k*64 + j0;
    #pragma unroll
    for (int jj = 0; jj < 16; jj++){ az[jj] += a*wz[jj]; ah[jj] += a*wh[jj]; }
  }
  #pragma unroll
  for (int k = 0; k < 64; k++){
    float hk  = Hs[node][k];
    float hrk = HRs[node][k];
    const float* wz = w + OFF_B + k*64 + j0;
    const float* wh = w + OFF_B + 8192 + k*64 + j0;
    #pragma unroll
    for (int jj = 0; jj < 16; jj++){ az[jj] += hk*wz[jj]; ah[jj] += hrk*wh[jj]; }
  }
  float hnew[16];
  #pragma unroll
  for (int jj = 0; jj < 16; jj++){
    float z = 1.f / (1.f + __expf(-az[jj]));
    float x = ah[jj];
    float e = __expf(-2.f * fabsf(x));
    float th = (1.f - e) / (1.f + e);
    th = (x < 0.f) ? -th : th;
    hnew[jj] = z * Hs[node][j0 + jj] + (1.f - z) * th;
  }
  __syncthreads();                          // all HRs reads done
  #pragma unroll
  for (int jj = 0; jj < 16; jj++) HRs[node][j0 + jj] = hnew[jj];
  __syncthreads();
  #pragma unroll
  for (int r = 0; r < 16; r++){
    int i = tid + 256*r; int n = i >> 6, k = i & 63; int gn = nb + n;
    if (gn < NN) h[gn*HH + k] = HRs[n][k];
  }
}

// ---------------- final projection h @ out_W + out_b -> f32 ----------------
__global__ __launch_bounds__(256) void out_kernel(const float* __restrict__ h,
                                                  const float* __restrict__ w,
                                                  float* __restrict__ out){
  __shared__ float Hl[16][65];
  __shared__ float Wl[64][16];
  __shared__ float bl[16];
  int tid = threadIdx.x;
  int nb = blockIdx.x*16;
  #pragma unroll
  for (int r = 0; r < 4; r++){
    int i = tid + 256*r;
    int n = i >> 6, k = i & 63; int gn = nb + n;
    Hl[n][k] = (gn < NN) ? h[gn*HH + k] : 0.f;
    Wl[(i >> 4) & 63][i & 15] = w[OFF_OW + i];
  }
  if (tid < 16) bl[tid] = w[OFF_OB + tid];
  __syncthreads();
  int n = tid >> 4; int o = tid & 15;
  float acc = bl[o];
  #pragma unroll
  for (int k = 0; k < 64; k++) acc += Hl[n][k] * Wl[k][o];
  int gn = nb + n;
  if (gn < NN) out[gn*OO + o] = acc;
}

extern "C" void kernel_launch(void* const* d_in, const int* in_sizes, int n_in,
                              void* d_out, int out_size, void* d_ws, size_t ws_size,
                              hipStream_t stream) {
  const float* xs = (const float*)d_in[0];
  const int*   ei = (const int*)d_in[1];
  float* out = (float*)d_out;
  char* ws = (char*)d_ws;
  // workspace layout (bytes); total 71,702,656 (same footprint as round-4-proven)
  ushort_t*     aggb   = (ushort_t*)(ws + 0);            // 19,200,000
  ushort_t*     xb     = (ushort_t*)(ws + 19200000);     // 19,200,000
  unsigned int* csrp   = (unsigned int*)(ws + 38400000); // 19,200,000
  float*        h      = (float*)(ws + 57600000);        // 12,800,000
  float*        dinv   = (float*)(ws + 70400000);        //  1,200,000
  int*          bcnt   = (int*)  (ws + 71600000);        // 6144
  int*          bstart = (int*)  (ws + 71608000);        // 6168
  int*          bcur   = (int*)  (ws + 71616000);        // 6144
  float*        wbuf   = (float*)(ws + 71624000);        // 78,656 -> end 71,702,656

  zero_kernel<<<(800000 + 255)/256, 256, 0, stream>>>((uint4*)(ws + 57600000), 800000); // h
  zero_kernel<<<2, 256, 0, stream>>>((uint4*)(ws + 71600000), 384);                      // bcnt
  cvt_kernel<<<(2400000 + 255)/256, 256, 0, stream>>>((const float4*)xs, (ushort4*)xb, 2400000);
  prep_kernel<<<(WBUF_N + 255)/256, 256, 0, stream>>>(d_in[2],d_in[3],d_in[4],d_in[5],
      d_in[6],d_in[7],d_in[8],d_in[9],d_in[10],d_in[11],d_in[12],d_in[13],d_in[14],d_in[15],
      wbuf);
  hist_kernel<<<dim3((EE + CHUNK-1)/CHUNK, TT), 256, 0, stream>>>(ei, bcnt);
  bscan_kernel<<<TT, 256, 0, stream>>>(bcnt, bstart, bcur);
  scatter_kernel<<<dim3((EE + CHUNK-1)/CHUNK, TT), 256, 0, stream>>>(ei, bcur, csrp);
  degdinv_kernel<<<dim3(NB, TT), 256, 0, stream>>>(csrp, bstart, dinv);
  gatherb_kernel<<<dim3(NB, TT), 256, 0, stream>>>(xs, xb, dinv, csrp, bstart, aggb);
  for (int t = 0; t < TT; t++)
    gate_kernel<<<(NN + 63)/64, 256, 0, stream>>>(aggb + (size_t)t*NN*FF, h, wbuf);
  out_kernel<<<NN/16, 256, 0, stream>>>(h, wbuf, out);
}